// Round 1
// baseline (240.281 us; speedup 1.0000x reference)
//
#include <hip/hip_runtime.h>

#define NN   128
#define NB   512
#define NMAT 2560
#define L2E  1.4426950408889634f

__device__ __forceinline__ float fexp2(float x){ float r; asm("v_exp_f32 %0, %1" : "=v"(r) : "v"(x)); return r; }
__device__ __forceinline__ float flog2(float x){ float r; asm("v_log_f32 %0, %1" : "=v"(r) : "v"(x)); return r; }
__device__ __forceinline__ float frcp (float x){ float r; asm("v_rcp_f32 %0, %1" : "=v"(r) : "v"(x)); return r; }

// ---------------------------------------------------------------------------
// Kernel 1: log_alpha (pre-scaled by log2(e)) -> workspace [512][128][128] f32
// la[b,r,c] = (sum_l relu(x[b,r]*w1[l]+b1[l]) * w2[c,l] + b2[c]) * log2(e)
// Grid: 1024 blocks (b, row-half), 256 threads; thread tile = 4 rows x 8 cols.
// w2 rows read via global dwordx4 (w2 is 64KB, L1/L2 resident).
// ---------------------------------------------------------------------------
__global__ __launch_bounds__(256) void mlp_la_kernel(
    const float* __restrict__ x,  const float* __restrict__ w1,
    const float* __restrict__ b1, const float* __restrict__ w2,
    const float* __restrict__ b2, float* __restrict__ la)
{
    const int t   = threadIdx.x;
    const int blk = blockIdx.x;            // 0..1023
    const int b   = blk >> 1;
    const int rh  = blk & 1;
    const int tr  = t >> 4, tc = t & 15;
    const int r0  = rh * 64 + tr * 4;
    const int c0  = tc * 8;

    float xv[4];
#pragma unroll
    for (int i = 0; i < 4; i++) xv[i] = x[b * NN + r0 + i];

    float acc[4][8];
#pragma unroll
    for (int i = 0; i < 4; i++)
#pragma unroll
        for (int j = 0; j < 8; j++) acc[i][j] = 0.f;

    for (int l4 = 0; l4 < NN; l4 += 4) {
        float4 w1v = *(const float4*)(w1 + l4);   // uniform -> scalarized
        float4 b1v = *(const float4*)(b1 + l4);
        float4 w2v[8];
#pragma unroll
        for (int j = 0; j < 8; j++)
            w2v[j] = *(const float4*)(w2 + (c0 + j) * NN + l4);
        const float* w1p = (const float*)&w1v;
        const float* b1p = (const float*)&b1v;
#pragma unroll
        for (int d = 0; d < 4; d++) {
            float h[4];
#pragma unroll
            for (int i = 0; i < 4; i++)
                h[i] = fmaxf(fmaf(xv[i], w1p[d], b1p[d]), 0.f);
#pragma unroll
            for (int j = 0; j < 8; j++) {
                float w = ((const float*)&w2v[j])[d];
#pragma unroll
                for (int i = 0; i < 4; i++)
                    acc[i][j] = fmaf(h[i], w, acc[i][j]);
            }
        }
    }

    float4 b2a = *(const float4*)(b2 + c0);
    float4 b2b = *(const float4*)(b2 + c0 + 4);
    const float* bp0 = (const float*)&b2a;
    const float* bp1 = (const float*)&b2b;
    float* lb = la + ((size_t)b * NN + r0) * NN + c0;
#pragma unroll
    for (int i = 0; i < 4; i++) {
        float4 o0, o1;
        o0.x = (acc[i][0] + bp0[0]) * L2E;
        o0.y = (acc[i][1] + bp0[1]) * L2E;
        o0.z = (acc[i][2] + bp0[2]) * L2E;
        o0.w = (acc[i][3] + bp0[3]) * L2E;
        o1.x = (acc[i][4] + bp1[0]) * L2E;
        o1.y = (acc[i][5] + bp1[1]) * L2E;
        o1.z = (acc[i][6] + bp1[2]) * L2E;
        o1.w = (acc[i][7] + bp1[3]) * L2E;
        *(float4*)(lb + i * NN)     = o0;
        *(float4*)(lb + i * NN + 4) = o1;
    }
}

// ---------------------------------------------------------------------------
// Kernel 2: Sinkhorn in potential form, base-2 log domain.
// One block per matrix (2560). 256 threads, 8x8 elements each (E in 64 VGPRs).
//   init: R1 = row-lse2(y0) (max-stabilized), E = 2^(y0-R1) <= 1, u = 1
//   k = 1..10:  t[c] = 1 / sum_r E*u   (LDS partial reduce)
//               u[r] = 1 / sum_c E*t   (shuffle reduce; skipped at k=10)
//   out[m][c][r] = E[r][c] * u[r] * t[c]   (transposed write, coalesced)
// ---------------------------------------------------------------------------
__global__ __launch_bounds__(256) void sinkhorn_kernel(
    const float* __restrict__ la, const float* __restrict__ noise,
    float* __restrict__ out)
{
    __shared__ float part[16][132];   // +4 pad: conflict-free b128 writes
    __shared__ float tbuf[128];

    const int m  = blockIdx.x;        // 0..2559
    const int b  = m & (NB - 1);
    const int t  = threadIdx.x;
    const int tr = t >> 4, tc = t & 15;
    const int r0 = tr * 8, c0 = tc * 8;

    const float* lab = la    + (size_t)b * NN * NN;
    const float* nb  = noise + (size_t)m * NN * NN;

    float E[8][8];
#pragma unroll
    for (int i = 0; i < 8; i++) {
        const float* lr = lab + (r0 + i) * NN + c0;
        const float* nr = nb  + (r0 + i) * NN + c0;
        float4 a0 = *(const float4*)(lr);
        float4 a1 = *(const float4*)(lr + 4);
        float4 n0 = *(const float4*)(nr);
        float4 n1 = *(const float4*)(nr + 4);
        E[i][0] = fmaf(n0.x, L2E, a0.x);
        E[i][1] = fmaf(n0.y, L2E, a0.y);
        E[i][2] = fmaf(n0.z, L2E, a0.z);
        E[i][3] = fmaf(n0.w, L2E, a0.w);
        E[i][4] = fmaf(n1.x, L2E, a1.x);
        E[i][5] = fmaf(n1.y, L2E, a1.y);
        E[i][6] = fmaf(n1.z, L2E, a1.z);
        E[i][7] = fmaf(n1.w, L2E, a1.w);
    }

    // init: row logsumexp2 with max; E = 2^(y0 - R1)
#pragma unroll
    for (int i = 0; i < 8; i++) {
        float mx = E[i][0];
#pragma unroll
        for (int j = 1; j < 8; j++) mx = fmaxf(mx, E[i][j]);
#pragma unroll
        for (int s = 1; s < 16; s <<= 1) mx = fmaxf(mx, __shfl_xor(mx, s));
        float sm = 0.f;
#pragma unroll
        for (int j = 0; j < 8; j++) sm += fexp2(E[i][j] - mx);
#pragma unroll
        for (int s = 1; s < 16; s <<= 1) sm += __shfl_xor(sm, s);
        float R1 = mx + flog2(sm);
#pragma unroll
        for (int j = 0; j < 8; j++) E[i][j] = fexp2(E[i][j] - R1);
    }

    float u[8];
#pragma unroll
    for (int i = 0; i < 8; i++) u[i] = 1.f;
    float tj[8];

    for (int k = 0; k < 10; k++) {
        // ---- column pass: t[c] = 1 / sum_r E*u ----
        float loc[8];
#pragma unroll
        for (int j = 0; j < 8; j++) {
            float s = 0.f;
#pragma unroll
            for (int i = 0; i < 8; i++) s = fmaf(E[i][j], u[i], s);
            loc[j] = s;
        }
        *(float4*)&part[tr][c0]     = make_float4(loc[0], loc[1], loc[2], loc[3]);
        *(float4*)&part[tr][c0 + 4] = make_float4(loc[4], loc[5], loc[6], loc[7]);
        __syncthreads();
        {
            const int col = t >> 1;
            const int p0  = (t & 1) * 8;
            float cs = 0.f;
#pragma unroll
            for (int p = 0; p < 8; p++) cs += part[p0 + p][col];
            cs += __shfl_xor(cs, 1);
            if ((t & 1) == 0) tbuf[col] = frcp(cs);
        }
        __syncthreads();
        {
            float4 t0 = *(const float4*)&tbuf[c0];
            float4 t1 = *(const float4*)&tbuf[c0 + 4];
            tj[0] = t0.x; tj[1] = t0.y; tj[2] = t0.z; tj[3] = t0.w;
            tj[4] = t1.x; tj[5] = t1.y; tj[6] = t1.z; tj[7] = t1.w;
        }
        // ---- row pass: u[r] = 1 / sum_c E*t (skip after last col pass) ----
        if (k < 9) {
#pragma unroll
            for (int i = 0; i < 8; i++) {
                float s = 0.f;
#pragma unroll
                for (int j = 0; j < 8; j++) s = fmaf(E[i][j], tj[j], s);
#pragma unroll
                for (int sf = 1; sf < 16; sf <<= 1) s += __shfl_xor(s, sf);
                u[i] = frcp(s);
            }
        }
    }

    // output (transposed): out[m][c][r] = E[r][c]*u[r]*t[c]
    float* ob = out + (size_t)m * NN * NN;
#pragma unroll
    for (int j = 0; j < 8; j++) {
        float4 v0, v1;
        v0.x = E[0][j] * u[0] * tj[j];
        v0.y = E[1][j] * u[1] * tj[j];
        v0.z = E[2][j] * u[2] * tj[j];
        v0.w = E[3][j] * u[3] * tj[j];
        v1.x = E[4][j] * u[4] * tj[j];
        v1.y = E[5][j] * u[5] * tj[j];
        v1.z = E[6][j] * u[6] * tj[j];
        v1.w = E[7][j] * u[7] * tj[j];
        *(float4*)(ob + (c0 + j) * NN + r0)     = v0;
        *(float4*)(ob + (c0 + j) * NN + r0 + 4) = v1;
    }
}

extern "C" void kernel_launch(void* const* d_in, const int* in_sizes, int n_in,
                              void* d_out, int out_size, void* d_ws, size_t ws_size,
                              hipStream_t stream) {
    const float* x     = (const float*)d_in[0];
    const float* w1    = (const float*)d_in[1];
    const float* b1    = (const float*)d_in[2];
    const float* w2    = (const float*)d_in[3];
    const float* b2    = (const float*)d_in[4];
    const float* noise = (const float*)d_in[5];
    float* out = (float*)d_out;
    float* la  = (float*)d_ws;   // needs 512*128*128*4 = 33.5 MB

    hipLaunchKernelGGL(mlp_la_kernel, dim3(1024), dim3(256), 0, stream,
                       x, w1, b1, w2, b2, la);
    hipLaunchKernelGGL(sinkhorn_kernel, dim3(NMAT), dim3(256), 0, stream,
                       la, noise, out);
}

// Round 2
// 144.473 us; speedup vs baseline: 1.6632x; 1.6632x over previous
//
#include <hip/hip_runtime.h>

#define NN   128
#define NB   512
#define NMAT 2560
#define L2E  1.4426950408889634f

typedef __attribute__((ext_vector_type(4))) float  f32x4;
typedef __attribute__((ext_vector_type(4))) int    i32x4;
typedef __attribute__((ext_vector_type(8))) ushort u16x8;

__device__ __forceinline__ float fexp2(float x){ float r; asm("v_exp_f32 %0, %1" : "=v"(r) : "v"(x)); return r; }
__device__ __forceinline__ float flog2(float x){ float r; asm("v_log_f32 %0, %1" : "=v"(r) : "v"(x)); return r; }
__device__ __forceinline__ float frcp (float x){ float r; asm("v_rcp_f32 %0, %1" : "=v"(r) : "v"(x)); return r; }

__device__ __forceinline__ ushort f2bf(float f){
    unsigned u = __float_as_uint(f);
    unsigned r = (u + 0x7FFFu + ((u >> 16) & 1u)) >> 16;
    return (ushort)r;
}
__device__ __forceinline__ float bf2f(ushort h){ return __uint_as_float(((unsigned)h) << 16); }

#define MFMA16(acc, a, b) \
    asm("v_mfma_f32_16x16x32_bf16 %0, %1, %2, %0" : "+v"(acc) : "v"(a), "v"(b))

// ---------------------------------------------------------------------------
// Prep kernel: permute w2*log2e into MFMA B-fragment order, split bf16 hi/lo.
// B_frag[ct][ks][lane][v] = bf16split( w2[ct*16+(lane&15)][ks*32+8*(lane>>4)+v] * L2E )
// Also b2s[c] = b2[c]*L2E. Grid 8 x 256 (one fragment per thread).
// ---------------------------------------------------------------------------
__global__ __launch_bounds__(256) void prep_kernel(
    const float* __restrict__ w2, const float* __restrict__ b2,
    ushort* __restrict__ Bhi, ushort* __restrict__ Blo, float* __restrict__ b2s)
{
    int fid = blockIdx.x * 256 + threadIdx.x;    // 0..2047
    int ct = fid >> 8, ks = (fid >> 6) & 3, lane = fid & 63;
    int c  = ct * 16 + (lane & 15);
    int k0 = ks * 32 + ((lane >> 4) << 3);
    u16x8 hi, lo;
#pragma unroll
    for (int j = 0; j < 8; j++) {
        float v = w2[c * NN + k0 + j] * L2E;
        ushort h = f2bf(v);
        hi[j] = h;
        lo[j] = f2bf(v - bf2f(h));
    }
    *(u16x8*)(Bhi + (size_t)fid * 8) = hi;
    *(u16x8*)(Blo + (size_t)fid * 8) = lo;
    if (fid < NN) b2s[fid] = b2[fid] * L2E;
}

// ---------------------------------------------------------------------------
// MLP -> la via MFMA (split bf16: hi@whi + hi@wlo + lo@whi).
// Grid 1024: block = (b, row-half of 64). 4 waves; wave w owns row-tile
// rows rh*64 + w*16 .. +15. Each lane computes exactly its A-fragment h
// values in-register (row = lane&15, k = 8*(lane>>4)+v) -> no LDS, no barrier.
// ---------------------------------------------------------------------------
__global__ __launch_bounds__(256) void mlp_mfma_kernel(
    const float* __restrict__ x,  const float* __restrict__ w1,
    const float* __restrict__ b1, const ushort* __restrict__ Bhi,
    const ushort* __restrict__ Blo, const float* __restrict__ b2s,
    float* __restrict__ la)
{
    const int t    = threadIdx.x;
    const int w    = t >> 6;
    const int lane = t & 63;
    const int blk  = blockIdx.x;
    const int b    = blk >> 1;
    const int rh   = blk & 1;

    const int r = rh * 64 + w * 16 + (lane & 15);
    const float xv = x[b * NN + r];

    // A fragments (hi/lo) for 4 K-steps, computed in-register.
    i32x4 Ahi[4], Alo[4];
#pragma unroll
    for (int ks = 0; ks < 4; ks++) {
        const int l0 = ks * 32 + ((lane >> 4) << 3);
        float4 w1a = *(const float4*)(w1 + l0);
        float4 w1b = *(const float4*)(w1 + l0 + 4);
        float4 b1a = *(const float4*)(b1 + l0);
        float4 b1b = *(const float4*)(b1 + l0 + 4);
        float h[8];
        h[0] = fmaxf(fmaf(xv, w1a.x, b1a.x), 0.f);
        h[1] = fmaxf(fmaf(xv, w1a.y, b1a.y), 0.f);
        h[2] = fmaxf(fmaf(xv, w1a.z, b1a.z), 0.f);
        h[3] = fmaxf(fmaf(xv, w1a.w, b1a.w), 0.f);
        h[4] = fmaxf(fmaf(xv, w1b.x, b1b.x), 0.f);
        h[5] = fmaxf(fmaf(xv, w1b.y, b1b.y), 0.f);
        h[6] = fmaxf(fmaf(xv, w1b.z, b1b.z), 0.f);
        h[7] = fmaxf(fmaf(xv, w1b.w, b1b.w), 0.f);
#pragma unroll
        for (int p = 0; p < 4; p++) {
            ushort h0 = f2bf(h[2 * p]);
            ushort h1 = f2bf(h[2 * p + 1]);
            ushort l0e = f2bf(h[2 * p]     - bf2f(h0));
            ushort l1e = f2bf(h[2 * p + 1] - bf2f(h1));
            ((int*)&Ahi[ks])[p] = ((int)h1 << 16) | (int)h0;
            ((int*)&Alo[ks])[p] = ((int)l1e << 16) | (int)l0e;
        }
    }

    f32x4 acc[8];
#pragma unroll
    for (int ct = 0; ct < 8; ct++) acc[ct] = (f32x4){0.f, 0.f, 0.f, 0.f};

    asm volatile("s_nop 7");   // VALU->MFMA settle (cheap insurance)

#pragma unroll
    for (int ks = 0; ks < 4; ks++) {
#pragma unroll
        for (int ct = 0; ct < 8; ct++) {
            const size_t off = ((size_t)(ct * 4 + ks) * 64 + lane) * 8;
            i32x4 bh = *(const i32x4*)(Bhi + off);
            i32x4 bl = *(const i32x4*)(Blo + off);
            MFMA16(acc[ct], Ahi[ks], bh);
            MFMA16(acc[ct], Ahi[ks], bl);
            MFMA16(acc[ct], Alo[ks], bh);
        }
    }

    asm volatile("s_nop 7");   // MFMA->VALU hazard
    asm volatile("s_nop 7");
    asm volatile("s_nop 3");

    // Epilogue: C layout col = lane&15, row = (lane>>4)*4 + q.
    const int row0 = b * NN + rh * 64 + w * 16 + (lane >> 4) * 4;
    const int col  = lane & 15;
#pragma unroll
    for (int ct = 0; ct < 8; ct++) {
        float bb = b2s[ct * 16 + col];
        float* lp = la + (size_t)row0 * NN + ct * 16 + col;
#pragma unroll
        for (int q = 0; q < 4; q++)
            lp[(size_t)q * NN] = acc[ct][q] + bb;
    }
}

// ---------------------------------------------------------------------------
// Kernel 2: Sinkhorn in potential form, base-2 log domain (unchanged).
// ---------------------------------------------------------------------------
__global__ __launch_bounds__(256) void sinkhorn_kernel(
    const float* __restrict__ la, const float* __restrict__ noise,
    float* __restrict__ out)
{
    __shared__ float part[16][132];
    __shared__ float tbuf[128];

    const int m  = blockIdx.x;
    const int b  = m & (NB - 1);
    const int t  = threadIdx.x;
    const int tr = t >> 4, tc = t & 15;
    const int r0 = tr * 8, c0 = tc * 8;

    const float* lab = la    + (size_t)b * NN * NN;
    const float* nb  = noise + (size_t)m * NN * NN;

    float E[8][8];
#pragma unroll
    for (int i = 0; i < 8; i++) {
        const float* lr = lab + (r0 + i) * NN + c0;
        const float* nr = nb  + (r0 + i) * NN + c0;
        float4 a0 = *(const float4*)(lr);
        float4 a1 = *(const float4*)(lr + 4);
        float4 n0 = *(const float4*)(nr);
        float4 n1 = *(const float4*)(nr + 4);
        E[i][0] = fmaf(n0.x, L2E, a0.x);
        E[i][1] = fmaf(n0.y, L2E, a0.y);
        E[i][2] = fmaf(n0.z, L2E, a0.z);
        E[i][3] = fmaf(n0.w, L2E, a0.w);
        E[i][4] = fmaf(n1.x, L2E, a1.x);
        E[i][5] = fmaf(n1.y, L2E, a1.y);
        E[i][6] = fmaf(n1.z, L2E, a1.z);
        E[i][7] = fmaf(n1.w, L2E, a1.w);
    }

#pragma unroll
    for (int i = 0; i < 8; i++) {
        float mx = E[i][0];
#pragma unroll
        for (int j = 1; j < 8; j++) mx = fmaxf(mx, E[i][j]);
#pragma unroll
        for (int s = 1; s < 16; s <<= 1) mx = fmaxf(mx, __shfl_xor(mx, s));
        float sm = 0.f;
#pragma unroll
        for (int j = 0; j < 8; j++) sm += fexp2(E[i][j] - mx);
#pragma unroll
        for (int s = 1; s < 16; s <<= 1) sm += __shfl_xor(sm, s);
        float R1 = mx + flog2(sm);
#pragma unroll
        for (int j = 0; j < 8; j++) E[i][j] = fexp2(E[i][j] - R1);
    }

    float u[8];
#pragma unroll
    for (int i = 0; i < 8; i++) u[i] = 1.f;
    float tj[8];

    for (int k = 0; k < 10; k++) {
        float loc[8];
#pragma unroll
        for (int j = 0; j < 8; j++) {
            float s = 0.f;
#pragma unroll
            for (int i = 0; i < 8; i++) s = fmaf(E[i][j], u[i], s);
            loc[j] = s;
        }
        *(float4*)&part[tr][c0]     = make_float4(loc[0], loc[1], loc[2], loc[3]);
        *(float4*)&part[tr][c0 + 4] = make_float4(loc[4], loc[5], loc[6], loc[7]);
        __syncthreads();
        {
            const int col = t >> 1;
            const int p0  = (t & 1) * 8;
            float cs = 0.f;
#pragma unroll
            for (int p = 0; p < 8; p++) cs += part[p0 + p][col];
            cs += __shfl_xor(cs, 1);
            if ((t & 1) == 0) tbuf[col] = frcp(cs);
        }
        __syncthreads();
        {
            float4 t0 = *(const float4*)&tbuf[c0];
            float4 t1 = *(const float4*)&tbuf[c0 + 4];
            tj[0] = t0.x; tj[1] = t0.y; tj[2] = t0.z; tj[3] = t0.w;
            tj[4] = t1.x; tj[5] = t1.y; tj[6] = t1.z; tj[7] = t1.w;
        }
        if (k < 9) {
#pragma unroll
            for (int i = 0; i < 8; i++) {
                float s = 0.f;
#pragma unroll
                for (int j = 0; j < 8; j++) s = fmaf(E[i][j], tj[j], s);
#pragma unroll
                for (int sf = 1; sf < 16; sf <<= 1) s += __shfl_xor(s, sf);
                u[i] = frcp(s);
            }
        }
    }

    float* ob = out + (size_t)m * NN * NN;
#pragma unroll
    for (int j = 0; j < 8; j++) {
        float4 v0, v1;
        v0.x = E[0][j] * u[0] * tj[j];
        v0.y = E[1][j] * u[1] * tj[j];
        v0.z = E[2][j] * u[2] * tj[j];
        v0.w = E[3][j] * u[3] * tj[j];
        v1.x = E[4][j] * u[4] * tj[j];
        v1.y = E[5][j] * u[5] * tj[j];
        v1.z = E[6][j] * u[6] * tj[j];
        v1.w = E[7][j] * u[7] * tj[j];
        *(float4*)(ob + (c0 + j) * NN + r0)     = v0;
        *(float4*)(ob + (c0 + j) * NN + r0 + 4) = v1;
    }
}

extern "C" void kernel_launch(void* const* d_in, const int* in_sizes, int n_in,
                              void* d_out, int out_size, void* d_ws, size_t ws_size,
                              hipStream_t stream) {
    const float* x     = (const float*)d_in[0];
    const float* w1    = (const float*)d_in[1];
    const float* b1    = (const float*)d_in[2];
    const float* w2    = (const float*)d_in[3];
    const float* b2    = (const float*)d_in[4];
    const float* noise = (const float*)d_in[5];
    float* out = (float*)d_out;

    char* ws  = (char*)d_ws;
    float*  la  = (float*)ws;                         // 33,554,432 B
    ushort* Bhi = (ushort*)(ws + 33554432);           // 32 KB
    ushort* Blo = (ushort*)(ws + 33554432 + 32768);   // 32 KB
    float*  b2s = (float*)(ws + 33554432 + 65536);    // 512 B

    hipLaunchKernelGGL(prep_kernel, dim3(8), dim3(256), 0, stream,
                       w2, b2, Bhi, Blo, b2s);
    hipLaunchKernelGGL(mlp_mfma_kernel, dim3(1024), dim3(256), 0, stream,
                       x, w1, b1, Bhi, Blo, b2s, la);
    hipLaunchKernelGGL(sinkhorn_kernel, dim3(NMAT), dim3(256), 0, stream,
                       la, noise, out);
}

// Round 3
// 132.352 us; speedup vs baseline: 1.8155x; 1.0916x over previous
//
#include <hip/hip_runtime.h>

#define NN   128
#define NB   512
#define NMAT 2560
#define L2E  1.4426950408889634f

typedef __attribute__((ext_vector_type(4))) float  f32x4;
typedef __attribute__((ext_vector_type(4))) int    i32x4;
typedef __attribute__((ext_vector_type(8))) ushort u16x8;

__device__ __forceinline__ float fexp2(float x){ float r; asm("v_exp_f32 %0, %1" : "=v"(r) : "v"(x)); return r; }
__device__ __forceinline__ float flog2(float x){ float r; asm("v_log_f32 %0, %1" : "=v"(r) : "v"(x)); return r; }
__device__ __forceinline__ float frcp (float x){ float r; asm("v_rcp_f32 %0, %1" : "=v"(r) : "v"(x)); return r; }

__device__ __forceinline__ ushort f2bf(float f){
    unsigned u = __float_as_uint(f);
    unsigned r = (u + 0x7FFFu + ((u >> 16) & 1u)) >> 16;
    return (ushort)r;
}
__device__ __forceinline__ float bf2f(ushort h){ return __uint_as_float(((unsigned)h) << 16); }

#define MFMA16(acc, a, b) \
    asm("v_mfma_f32_16x16x32_bf16 %0, %1, %2, %0" : "+v"(acc) : "v"(a), "v"(b))

// ---------------------------------------------------------------------------
// Prep kernel: permute w2*log2e into MFMA B-fragment order, split bf16 hi/lo.
// ---------------------------------------------------------------------------
__global__ __launch_bounds__(256) void prep_kernel(
    const float* __restrict__ w2, const float* __restrict__ b2,
    ushort* __restrict__ Bhi, ushort* __restrict__ Blo, float* __restrict__ b2s)
{
    int fid = blockIdx.x * 256 + threadIdx.x;    // 0..2047
    int ct = fid >> 8, ks = (fid >> 6) & 3, lane = fid & 63;
    int c  = ct * 16 + (lane & 15);
    int k0 = ks * 32 + ((lane >> 4) << 3);
    u16x8 hi, lo;
#pragma unroll
    for (int j = 0; j < 8; j++) {
        float v = w2[c * NN + k0 + j] * L2E;
        ushort h = f2bf(v);
        hi[j] = h;
        lo[j] = f2bf(v - bf2f(h));
    }
    *(u16x8*)(Bhi + (size_t)fid * 8) = hi;
    *(u16x8*)(Blo + (size_t)fid * 8) = lo;
    if (fid < NN) b2s[fid] = b2[fid] * L2E;
}

// ---------------------------------------------------------------------------
// MLP -> la via MFMA (split bf16: hi@whi + hi@wlo + lo@whi). No LDS/barriers.
// ---------------------------------------------------------------------------
__global__ __launch_bounds__(256) void mlp_mfma_kernel(
    const float* __restrict__ x,  const float* __restrict__ w1,
    const float* __restrict__ b1, const ushort* __restrict__ Bhi,
    const ushort* __restrict__ Blo, const float* __restrict__ b2s,
    float* __restrict__ la)
{
    const int t    = threadIdx.x;
    const int w    = t >> 6;
    const int lane = t & 63;
    const int blk  = blockIdx.x;
    const int b    = blk >> 1;
    const int rh   = blk & 1;

    const int r = rh * 64 + w * 16 + (lane & 15);
    const float xv = x[b * NN + r];

    i32x4 Ahi[4], Alo[4];
#pragma unroll
    for (int ks = 0; ks < 4; ks++) {
        const int l0 = ks * 32 + ((lane >> 4) << 3);
        float4 w1a = *(const float4*)(w1 + l0);
        float4 w1b = *(const float4*)(w1 + l0 + 4);
        float4 b1a = *(const float4*)(b1 + l0);
        float4 b1b = *(const float4*)(b1 + l0 + 4);
        float h[8];
        h[0] = fmaxf(fmaf(xv, w1a.x, b1a.x), 0.f);
        h[1] = fmaxf(fmaf(xv, w1a.y, b1a.y), 0.f);
        h[2] = fmaxf(fmaf(xv, w1a.z, b1a.z), 0.f);
        h[3] = fmaxf(fmaf(xv, w1a.w, b1a.w), 0.f);
        h[4] = fmaxf(fmaf(xv, w1b.x, b1b.x), 0.f);
        h[5] = fmaxf(fmaf(xv, w1b.y, b1b.y), 0.f);
        h[6] = fmaxf(fmaf(xv, w1b.z, b1b.z), 0.f);
        h[7] = fmaxf(fmaf(xv, w1b.w, b1b.w), 0.f);
#pragma unroll
        for (int p = 0; p < 4; p++) {
            ushort h0 = f2bf(h[2 * p]);
            ushort h1 = f2bf(h[2 * p + 1]);
            ushort l0e = f2bf(h[2 * p]     - bf2f(h0));
            ushort l1e = f2bf(h[2 * p + 1] - bf2f(h1));
            ((int*)&Ahi[ks])[p] = ((int)h1 << 16) | (int)h0;
            ((int*)&Alo[ks])[p] = ((int)l1e << 16) | (int)l0e;
        }
    }

    f32x4 acc[8];
#pragma unroll
    for (int ct = 0; ct < 8; ct++) acc[ct] = (f32x4){0.f, 0.f, 0.f, 0.f};

    asm volatile("s_nop 7");

#pragma unroll
    for (int ks = 0; ks < 4; ks++) {
#pragma unroll
        for (int ct = 0; ct < 8; ct++) {
            const size_t off = ((size_t)(ct * 4 + ks) * 64 + lane) * 8;
            i32x4 bh = *(const i32x4*)(Bhi + off);
            i32x4 bl = *(const i32x4*)(Blo + off);
            MFMA16(acc[ct], Ahi[ks], bh);
            MFMA16(acc[ct], Ahi[ks], bl);
            MFMA16(acc[ct], Alo[ks], bh);
        }
    }

    asm volatile("s_nop 7");
    asm volatile("s_nop 7");
    asm volatile("s_nop 3");

    const int row0 = b * NN + rh * 64 + w * 16 + (lane >> 4) * 4;
    const int col  = lane & 15;
#pragma unroll
    for (int ct = 0; ct < 8; ct++) {
        float bb = b2s[ct * 16 + col];
        float* lp = la + (size_t)row0 * NN + ct * 16 + col;
#pragma unroll
        for (int q = 0; q < 4; q++)
            lp[(size_t)q * NN] = acc[ct][q] + bb;
    }
}

// ---------------------------------------------------------------------------
// Kernel 2: Sinkhorn, potential form, base-2 log domain.
// NOW 512 threads/block: thread tile 4 rows x 8 cols (E = 32 VGPRs).
// tr = t>>4 (0..31) -> rows tr*4..tr*4+3 ; tc = t&15 -> cols tc*8..tc*8+7.
// Col reduce: 4 threads per column (consecutive lanes), shfl_xor(1,2).
// __launch_bounds__(512,6): cap VGPR ~84 -> 3 blocks (24 waves) per CU.
// ---------------------------------------------------------------------------
__global__ __launch_bounds__(512, 6) void sinkhorn_kernel(
    const float* __restrict__ la, const float* __restrict__ noise,
    float* __restrict__ out)
{
    __shared__ float part[32][132];   // partial col sums, padded stride
    __shared__ float tbuf[128];

    const int m  = blockIdx.x;
    const int b  = m & (NB - 1);
    const int t  = threadIdx.x;
    const int tr = t >> 4, tc = t & 15;
    const int r0 = tr * 4, c0 = tc * 8;

    const float* lab = la    + (size_t)b * NN * NN;
    const float* nb  = noise + (size_t)m * NN * NN;

    float E[4][8];
#pragma unroll
    for (int i = 0; i < 4; i++) {
        const float* lr = lab + (r0 + i) * NN + c0;
        const float* nr = nb  + (r0 + i) * NN + c0;
        float4 a0 = *(const float4*)(lr);
        float4 a1 = *(const float4*)(lr + 4);
        float4 n0 = *(const float4*)(nr);
        float4 n1 = *(const float4*)(nr + 4);
        E[i][0] = fmaf(n0.x, L2E, a0.x);
        E[i][1] = fmaf(n0.y, L2E, a0.y);
        E[i][2] = fmaf(n0.z, L2E, a0.z);
        E[i][3] = fmaf(n0.w, L2E, a0.w);
        E[i][4] = fmaf(n1.x, L2E, a1.x);
        E[i][5] = fmaf(n1.y, L2E, a1.y);
        E[i][6] = fmaf(n1.z, L2E, a1.z);
        E[i][7] = fmaf(n1.w, L2E, a1.w);
    }

    // init: row logsumexp2 (max-stabilized); E = 2^(y0 - R1) <= 1
#pragma unroll
    for (int i = 0; i < 4; i++) {
        float mx = E[i][0];
#pragma unroll
        for (int j = 1; j < 8; j++) mx = fmaxf(mx, E[i][j]);
#pragma unroll
        for (int s = 1; s < 16; s <<= 1) mx = fmaxf(mx, __shfl_xor(mx, s));
        float sm = 0.f;
#pragma unroll
        for (int j = 0; j < 8; j++) sm += fexp2(E[i][j] - mx);
#pragma unroll
        for (int s = 1; s < 16; s <<= 1) sm += __shfl_xor(sm, s);
        float R1 = mx + flog2(sm);
#pragma unroll
        for (int j = 0; j < 8; j++) E[i][j] = fexp2(E[i][j] - R1);
    }

    float u[4];
#pragma unroll
    for (int i = 0; i < 4; i++) u[i] = 1.f;
    float tj[8];

    for (int k = 0; k < 10; k++) {
        // ---- column pass: t[c] = 1 / sum_r E*u ----
        float loc[8];
#pragma unroll
        for (int j = 0; j < 8; j++) {
            float s = 0.f;
#pragma unroll
            for (int i = 0; i < 4; i++) s = fmaf(E[i][j], u[i], s);
            loc[j] = s;
        }
        *(float4*)&part[tr][c0]     = make_float4(loc[0], loc[1], loc[2], loc[3]);
        *(float4*)&part[tr][c0 + 4] = make_float4(loc[4], loc[5], loc[6], loc[7]);
        __syncthreads();
        {
            const int col = t >> 2;       // 0..127, 4 consecutive lanes per col
            const int q   = t & 3;
            float cs = 0.f;
#pragma unroll
            for (int p = 0; p < 8; p++) cs += part[q + 4 * p][col];
            cs += __shfl_xor(cs, 1);
            cs += __shfl_xor(cs, 2);
            if (q == 0) tbuf[col] = frcp(cs);
        }
        __syncthreads();
        {
            float4 t0 = *(const float4*)&tbuf[c0];
            float4 t1 = *(const float4*)&tbuf[c0 + 4];
            tj[0] = t0.x; tj[1] = t0.y; tj[2] = t0.z; tj[3] = t0.w;
            tj[4] = t1.x; tj[5] = t1.y; tj[6] = t1.z; tj[7] = t1.w;
        }
        // ---- row pass: u[r] = 1 / sum_c E*t (skipped after last col pass) --
        if (k < 9) {
#pragma unroll
            for (int i = 0; i < 4; i++) {
                float s = 0.f;
#pragma unroll
                for (int j = 0; j < 8; j++) s = fmaf(E[i][j], tj[j], s);
#pragma unroll
                for (int sf = 1; sf < 16; sf <<= 1) s += __shfl_xor(s, sf);
                u[i] = frcp(s);
            }
        }
    }

    // output (transposed): out[m][c][r] = E[r][c]*u[r]*t[c]
    float* ob = out + (size_t)m * NN * NN;
#pragma unroll
    for (int j = 0; j < 8; j++) {
        float4 v;
        v.x = E[0][j] * u[0] * tj[j];
        v.y = E[1][j] * u[1] * tj[j];
        v.z = E[2][j] * u[2] * tj[j];
        v.w = E[3][j] * u[3] * tj[j];
        *(float4*)(ob + (c0 + j) * NN + r0) = v;
    }
}

extern "C" void kernel_launch(void* const* d_in, const int* in_sizes, int n_in,
                              void* d_out, int out_size, void* d_ws, size_t ws_size,
                              hipStream_t stream) {
    const float* x     = (const float*)d_in[0];
    const float* w1    = (const float*)d_in[1];
    const float* b1    = (const float*)d_in[2];
    const float* w2    = (const float*)d_in[3];
    const float* b2    = (const float*)d_in[4];
    const float* noise = (const float*)d_in[5];
    float* out = (float*)d_out;

    char* ws  = (char*)d_ws;
    float*  la  = (float*)ws;                         // 33,554,432 B
    ushort* Bhi = (ushort*)(ws + 33554432);           // 32 KB
    ushort* Blo = (ushort*)(ws + 33554432 + 32768);   // 32 KB
    float*  b2s = (float*)(ws + 33554432 + 65536);    // 512 B

    hipLaunchKernelGGL(prep_kernel, dim3(8), dim3(256), 0, stream,
                       w2, b2, Bhi, Blo, b2s);
    hipLaunchKernelGGL(mlp_mfma_kernel, dim3(1024), dim3(256), 0, stream,
                       x, w1, b1, Bhi, Blo, b2s, la);
    hipLaunchKernelGGL(sinkhorn_kernel, dim3(NMAT), dim3(512), 0, stream,
                       la, noise, out);
}